// Round 1
// baseline (892.123 us; speedup 1.0000x reference)
//
#include <hip/hip_runtime.h>

#define HW 3136
#define WID 56
#define HEI 56
#define NCH 256
#define NB 16

// ---------------------------------------------------------------------------
// K1 / K2b: projection GEMM. src is NCHW (K=256 channels), weight [DOUT][256],
// bias [DOUT]. Output layout [n][p][DOUT] (channel-contiguous).
// Block: 256 threads, 32-pixel tile. Thread owns 2 output channels x 16 pixels.
// ---------------------------------------------------------------------------
template <int DOUT>
__global__ __launch_bounds__(256) void proj_kernel(const float* __restrict__ src,
                                                   const float* __restrict__ wgt,
                                                   const float* __restrict__ bias,
                                                   float* __restrict__ out) {
    int blk = blockIdx.x;
    int n = blk / (HW / 32);
    int p0 = (blk % (HW / 32)) * 32;
    int tid = threadIdx.x;

    __shared__ __align__(16) float tok[32][260];  // [pixel][k], stride 260 (16B-aligned rows)

    // ---- stage: tok[p][k] = src[n][k][p0+p], coalesced along p ----
    {
        int ps = tid & 31, kr = tid >> 5;  // 32 pixels x 8 k-rows per pass
        const float* sbase = src + (size_t)n * NCH * HW + p0 + ps;
        #pragma unroll
        for (int it = 0; it < 32; ++it) {
            int k = it * 8 + kr;
            tok[ps][k] = sbase[(size_t)k * HW];
        }
    }
    __syncthreads();

    int d0 = (tid & 127) * 2;       // output channel pair
    int pp0 = (tid >> 7) * 16;      // pixel half
    bool act = (d0 < DOUT);

    if (act) {
        float accA[16], accB[16];
        #pragma unroll
        for (int p = 0; p < 16; ++p) { accA[p] = bias[d0]; accB[p] = bias[d0 + 1]; }

        const float4* wA = (const float4*)(wgt + (size_t)d0 * 256);
        const float4* wB = (const float4*)(wgt + (size_t)(d0 + 1) * 256);
        for (int k4 = 0; k4 < 64; ++k4) {
            float4 a = wA[k4];
            float4 b = wB[k4];
            #pragma unroll
            for (int p = 0; p < 16; ++p) {
                float4 t = *(const float4*)&tok[pp0 + p][k4 * 4];
                accA[p] += a.x * t.x + a.y * t.y + a.z * t.z + a.w * t.w;
                accB[p] += b.x * t.x + b.y * t.y + b.z * t.z + b.w * t.w;
            }
        }
        #pragma unroll
        for (int p = 0; p < 16; ++p) {
            float2 v = make_float2(accA[p], accB[p]);
            *(float2*)&out[((size_t)n * HW + p0 + pp0 + p) * DOUT + d0] = v;
        }
    }
}

// ---------------------------------------------------------------------------
// K2a: grouped 3x3 conv, feature_group_count = C.
// Output channel c consumes cat channels 2c, 2c+1; cat = [input(256), ref(256)].
// Lanes along x => every tap load is coalesced. Output NCHW.
// Grid: NB * HEI * 64 blocks; thread = (x = tid&63, c = cb*4 + tid>>6).
// ---------------------------------------------------------------------------
__global__ __launch_bounds__(256) void dwconv_kernel(const float* __restrict__ input,
                                                     const float* __restrict__ ref,
                                                     const float* __restrict__ dw_w,
                                                     const float* __restrict__ dw_b,
                                                     float* __restrict__ out) {
    int blk = blockIdx.x;
    int cb = blk & 63;
    int y = (blk >> 6) % HEI;
    int n = blk / (64 * HEI);
    int tid = threadIdx.x;
    int x = tid & 63;
    int c = cb * 4 + (tid >> 6);

    const float* src = (c < 128) ? input : ref;
    int ch0 = (c < 128) ? (2 * c) : (2 * c - 256);

    float wreg[18];
    #pragma unroll
    for (int i = 0; i < 18; ++i) wreg[i] = dw_w[c * 18 + i];

    if (x < WID) {
        float acc = dw_b[c];
        #pragma unroll
        for (int i = 0; i < 2; ++i) {
            const float* base = src + (size_t)(n * NCH + ch0 + i) * HW;
            #pragma unroll
            for (int ky = 0; ky < 3; ++ky) {
                int yy = y + ky - 1;
                if (yy >= 0 && yy < HEI) {
                    const float* row = base + yy * WID;
                    #pragma unroll
                    for (int kx = 0; kx < 3; ++kx) {
                        int xx = x + kx - 1;
                        float v = (xx >= 0 && xx < WID) ? row[xx] : 0.f;
                        acc += v * wreg[i * 9 + ky * 3 + kx];
                    }
                }
            }
        }
        out[(size_t)(n * NCH + c) * HW + y * WID + x] = acc;
    }
}

// ---------------------------------------------------------------------------
// K3: fused bilinear sampling + output projection.
// Phase 1: thread = (g = tid>>5, c' = tid&31); for each of 16 pixels, 9 points,
//          4 bilinear corners gathered from xv (NHWC, 128B-contiguous per group).
// Phase 2: mini-GEMM with out_w, NCHW store.
// ---------------------------------------------------------------------------
__global__ __launch_bounds__(256) void sample_out_kernel(const float* __restrict__ xv,
                                                         const float* __restrict__ om,
                                                         const float* __restrict__ out_w,
                                                         const float* __restrict__ out_b,
                                                         float* __restrict__ dout) {
    int blk = blockIdx.x;
    int n = blk / (HW / 16);
    int p0 = (blk % (HW / 16)) * 16;
    int tid = threadIdx.x;

    __shared__ __align__(16) float sout[16][260];

    int g = tid >> 5, cc = tid & 31;
    const float* xvg = xv + (size_t)n * HW * 256 + g * 32 + cc;

    for (int p = 0; p < 16; ++p) {
        int pix = p0 + p;
        int py = pix / WID, px = pix % WID;
        const float* ob = om + ((size_t)n * HW + pix) * 216 + g * 27;
        float acc = 0.f;
        #pragma unroll
        for (int pt = 0; pt < 9; ++pt) {
            float ox = ob[2 * pt];
            float oy = ob[2 * pt + 1];
            float m = ob[18 + pt];
            float iy = (float)(py + pt / 3 - 1) + oy;
            float ix = (float)(px + pt % 3 - 1) + ox;
            float fy0 = floorf(iy), fx0 = floorf(ix);
            float fy = iy - fy0, fx = ix - fx0;
            int y0 = (int)fy0, x0 = (int)fx0;
            #pragma unroll
            for (int dy = 0; dy < 2; ++dy) {
                #pragma unroll
                for (int dx = 0; dx < 2; ++dx) {
                    int yy = y0 + dy, xx = x0 + dx;
                    bool valid = (yy >= 0) & (yy < HEI) & (xx >= 0) & (xx < WID);
                    int yc = min(max(yy, 0), HEI - 1);
                    int xc = min(max(xx, 0), WID - 1);
                    float wv = (dy ? fy : 1.f - fy) * (dx ? fx : 1.f - fx);
                    float v = xvg[(size_t)(yc * WID + xc) * 256];
                    acc += (valid ? wv * m : 0.f) * v;
                }
            }
        }
        sout[p][tid] = acc;
    }
    __syncthreads();

    // ---- output projection: y[p][d] = out_b[d] + sum_c sout[p][c]*out_w[d][c] ----
    int d0 = (tid & 127) * 2;
    int pp0 = (tid >> 7) * 8;
    float accA[8], accB[8];
    #pragma unroll
    for (int p = 0; p < 8; ++p) { accA[p] = out_b[d0]; accB[p] = out_b[d0 + 1]; }

    const float4* wA = (const float4*)(out_w + (size_t)d0 * 256);
    const float4* wB = (const float4*)(out_w + (size_t)(d0 + 1) * 256);
    for (int k4 = 0; k4 < 64; ++k4) {
        float4 a = wA[k4];
        float4 b = wB[k4];
        #pragma unroll
        for (int p = 0; p < 8; ++p) {
            float4 t = *(const float4*)&sout[pp0 + p][k4 * 4];
            accA[p] += a.x * t.x + a.y * t.y + a.z * t.z + a.w * t.w;
            accB[p] += b.x * t.x + b.y * t.y + b.z * t.z + b.w * t.w;
        }
    }
    size_t ob0 = (size_t)(n * NCH + d0) * HW + p0 + pp0;
    #pragma unroll
    for (int p = 0; p < 8; ++p) dout[ob0 + p] = accA[p];
    #pragma unroll
    for (int p = 0; p < 8; ++p) dout[ob0 + HW + p] = accB[p];
}

extern "C" void kernel_launch(void* const* d_in, const int* in_sizes, int n_in,
                              void* d_out, int out_size, void* d_ws, size_t ws_size,
                              hipStream_t stream) {
    const float* ref     = (const float*)d_in[0];
    const float* input   = (const float*)d_in[1];
    const float* value_w = (const float*)d_in[2];
    const float* value_b = (const float*)d_in[3];
    const float* dw_w    = (const float*)d_in[4];
    const float* dw_b    = (const float*)d_in[5];
    const float* om_w    = (const float*)d_in[6];
    const float* om_b    = (const float*)d_in[7];
    const float* out_w   = (const float*)d_in[8];
    const float* out_b   = (const float*)d_in[9];
    float* out = (float*)d_out;

    float* xv  = (float*)d_ws;                       // [N][HW][256]  51.4 MB
    float* dwb = xv + (size_t)NB * HW * 256;         // [N][256][HW]  51.4 MB
    float* om  = dwb + (size_t)NB * HW * 256;        // [N][HW][216]  43.4 MB

    proj_kernel<256><<<NB * (HW / 32), 256, 0, stream>>>(input, value_w, value_b, xv);
    dwconv_kernel<<<NB * HEI * 64, 256, 0, stream>>>(input, ref, dw_w, dw_b, dwb);
    proj_kernel<216><<<NB * (HW / 32), 256, 0, stream>>>(dwb, om_w, om_b, om);
    sample_out_kernel<<<NB * (HW / 16), 256, 0, stream>>>(xv, om, out_w, out_b, out);
}

// Round 2
// 831.685 us; speedup vs baseline: 1.0727x; 1.0727x over previous
//
#include <hip/hip_runtime.h>

#define HW 3136
#define WID 56
#define HEI 56
#define NCH 256
#define NB 16

// ---------------------------------------------------------------------------
// K1 / K2b: projection GEMM. src is NCHW (K=256 channels), weight [DOUT][256],
// bias [DOUT]. Output layout [n][p][DOUT] (channel-contiguous).
// Block: 256 threads, 32-pixel tile. Thread owns 2 output channels x 16 pixels.
// ---------------------------------------------------------------------------
template <int DOUT>
__global__ __launch_bounds__(256) void proj_kernel(const float* __restrict__ src,
                                                   const float* __restrict__ wgt,
                                                   const float* __restrict__ bias,
                                                   float* __restrict__ out) {
    int blk = blockIdx.x;
    int n = blk / (HW / 32);
    int p0 = (blk % (HW / 32)) * 32;
    int tid = threadIdx.x;

    __shared__ __align__(16) float tok[32][260];  // [pixel][k], stride 260 (16B-aligned rows)

    // ---- stage: tok[p][k] = src[n][k][p0+p], coalesced along p ----
    {
        int ps = tid & 31, kr = tid >> 5;  // 32 pixels x 8 k-rows per pass
        const float* sbase = src + (size_t)n * NCH * HW + p0 + ps;
        #pragma unroll
        for (int it = 0; it < 32; ++it) {
            int k = it * 8 + kr;
            tok[ps][k] = sbase[(size_t)k * HW];
        }
    }
    __syncthreads();

    int d0 = (tid & 127) * 2;       // output channel pair
    int pp0 = (tid >> 7) * 16;      // pixel half
    bool act = (d0 < DOUT);

    if (act) {
        float accA[16], accB[16];
        #pragma unroll
        for (int p = 0; p < 16; ++p) { accA[p] = bias[d0]; accB[p] = bias[d0 + 1]; }

        const float4* wA = (const float4*)(wgt + (size_t)d0 * 256);
        const float4* wB = (const float4*)(wgt + (size_t)(d0 + 1) * 256);
        for (int k4 = 0; k4 < 64; ++k4) {
            float4 a = wA[k4];
            float4 b = wB[k4];
            #pragma unroll
            for (int p = 0; p < 16; ++p) {
                float4 t = *(const float4*)&tok[pp0 + p][k4 * 4];
                accA[p] += a.x * t.x + a.y * t.y + a.z * t.z + a.w * t.w;
                accB[p] += b.x * t.x + b.y * t.y + b.z * t.z + b.w * t.w;
            }
        }
        #pragma unroll
        for (int p = 0; p < 16; ++p) {
            float2 v = make_float2(accA[p], accB[p]);
            *(float2*)&out[((size_t)n * HW + p0 + pp0 + p) * DOUT + d0] = v;
        }
    }
}

// ---------------------------------------------------------------------------
// K2a: grouped 3x3 conv, feature_group_count = C.
// ---------------------------------------------------------------------------
__global__ __launch_bounds__(256) void dwconv_kernel(const float* __restrict__ input,
                                                     const float* __restrict__ ref,
                                                     const float* __restrict__ dw_w,
                                                     const float* __restrict__ dw_b,
                                                     float* __restrict__ out) {
    int blk = blockIdx.x;
    int cb = blk & 63;
    int y = (blk >> 6) % HEI;
    int n = blk / (64 * HEI);
    int tid = threadIdx.x;
    int x = tid & 63;
    int c = cb * 4 + (tid >> 6);

    const float* src = (c < 128) ? input : ref;
    int ch0 = (c < 128) ? (2 * c) : (2 * c - 256);

    float wreg[18];
    #pragma unroll
    for (int i = 0; i < 18; ++i) wreg[i] = dw_w[c * 18 + i];

    if (x < WID) {
        float acc = dw_b[c];
        #pragma unroll
        for (int i = 0; i < 2; ++i) {
            const float* base = src + (size_t)(n * NCH + ch0 + i) * HW;
            #pragma unroll
            for (int ky = 0; ky < 3; ++ky) {
                int yy = y + ky - 1;
                if (yy >= 0 && yy < HEI) {
                    const float* row = base + yy * WID;
                    #pragma unroll
                    for (int kx = 0; kx < 3; ++kx) {
                        int xx = x + kx - 1;
                        float v = (xx >= 0 && xx < WID) ? row[xx] : 0.f;
                        acc += v * wreg[i * 9 + ky * 3 + kx];
                    }
                }
            }
        }
        out[(size_t)(n * NCH + c) * HW + y * WID + x] = acc;
    }
}

// ---------------------------------------------------------------------------
// K3: fused bilinear sampling + output projection.
// Phase 0: precompute per (pix,g,pt): 4 bilinear weights (mask*valid folded)
//          + 4 clamped gather indices (yc*56+xc packed in ushort) -> LDS.
// Phase 1: thread = (pix = t>>4, gpair = (t>>3)&1, c4 = t&7); 4 groups x
//          4 channels per thread; per corner: 1 float4 gather + 4 FMA.
// Phase 2: mini-GEMM with out_w, NCHW store.
// ---------------------------------------------------------------------------
__global__ __launch_bounds__(256) void sample_out_kernel(const float* __restrict__ xv,
                                                         const float* __restrict__ om,
                                                         const float* __restrict__ out_w,
                                                         const float* __restrict__ out_b,
                                                         float* __restrict__ dout) {
    int blk = blockIdx.x;
    int n = blk / (HW / 16);
    int p0 = (blk % (HW / 16)) * 16;
    int tid = threadIdx.x;

    __shared__ __align__(16) float swt[1152][4];     // [pix*72 + g*9 + pt][corner]
    __shared__ __align__(8)  ushort soff[1152][4];   // packed yc*56+xc per corner
    __shared__ __align__(16) float sout[16][260];

    // ---- phase 0: weights/indices ----
    for (int i = tid; i < 1152; i += 256) {
        int pix = i / 72;
        int r = i % 72;
        int g = r / 9;
        int pt = r % 9;
        int glob = p0 + pix;
        int py = glob / WID, px = glob % WID;
        const float* ob = om + ((size_t)n * HW + glob) * 216 + g * 27;
        float ox = ob[2 * pt];
        float oy = ob[2 * pt + 1];
        float m = ob[18 + pt];
        float iy = (float)(py + pt / 3 - 1) + oy;
        float ix = (float)(px + pt % 3 - 1) + ox;
        float fy0 = floorf(iy), fx0 = floorf(ix);
        float fy = iy - fy0, fx = ix - fx0;
        int y0 = (int)fy0, x0 = (int)fx0;
        #pragma unroll
        for (int dy = 0; dy < 2; ++dy) {
            #pragma unroll
            for (int dx = 0; dx < 2; ++dx) {
                int yy = y0 + dy, xx = x0 + dx;
                bool valid = (yy >= 0) & (yy < HEI) & (xx >= 0) & (xx < WID);
                int yc = min(max(yy, 0), HEI - 1);
                int xc = min(max(xx, 0), WID - 1);
                float wv = (dy ? fy : 1.f - fy) * (dx ? fx : 1.f - fx) * m;
                swt[i][dy * 2 + dx] = valid ? wv : 0.f;
                soff[i][dy * 2 + dx] = (ushort)(yc * WID + xc);
            }
        }
    }
    __syncthreads();

    // ---- phase 1: gather-accumulate ----
    {
        int pix = tid >> 4;
        int gp = (tid >> 3) & 1;
        int c4 = tid & 7;
        float4 acc[4];
        #pragma unroll
        for (int i = 0; i < 4; ++i) acc[i] = make_float4(0.f, 0.f, 0.f, 0.f);

        const float* xvb = xv + (size_t)n * HW * 256;
        #pragma unroll
        for (int i = 0; i < 4; ++i) {
            int g = gp + 2 * i;
            int widx = pix * 72 + g * 9;
            const float* xc = xvb + g * 32 + c4 * 4;
            #pragma unroll
            for (int pt = 0; pt < 9; ++pt) {
                float4 w = *(const float4*)&swt[widx + pt][0];
                ushort4 o = *(const ushort4*)&soff[widx + pt][0];
                float4 v0 = *(const float4*)(xc + (int)o.x * 256);
                float4 v1 = *(const float4*)(xc + (int)o.y * 256);
                float4 v2 = *(const float4*)(xc + (int)o.z * 256);
                float4 v3 = *(const float4*)(xc + (int)o.w * 256);
                acc[i].x += w.x * v0.x + w.y * v1.x + w.z * v2.x + w.w * v3.x;
                acc[i].y += w.x * v0.y + w.y * v1.y + w.z * v2.y + w.w * v3.y;
                acc[i].z += w.x * v0.z + w.y * v1.z + w.z * v2.z + w.w * v3.z;
                acc[i].w += w.x * v0.w + w.y * v1.w + w.z * v2.w + w.w * v3.w;
            }
        }
        #pragma unroll
        for (int i = 0; i < 4; ++i) {
            int g = gp + 2 * i;
            *(float4*)&sout[pix][g * 32 + c4 * 4] = acc[i];
        }
    }
    __syncthreads();

    // ---- phase 2: output projection ----
    int d0 = (tid & 127) * 2;
    int pp0 = (tid >> 7) * 8;
    float accA[8], accB[8];
    #pragma unroll
    for (int p = 0; p < 8; ++p) { accA[p] = out_b[d0]; accB[p] = out_b[d0 + 1]; }

    const float4* wA = (const float4*)(out_w + (size_t)d0 * 256);
    const float4* wB = (const float4*)(out_w + (size_t)(d0 + 1) * 256);
    for (int k4 = 0; k4 < 64; ++k4) {
        float4 a = wA[k4];
        float4 b = wB[k4];
        #pragma unroll
        for (int p = 0; p < 8; ++p) {
            float4 t = *(const float4*)&sout[pp0 + p][k4 * 4];
            accA[p] += a.x * t.x + a.y * t.y + a.z * t.z + a.w * t.w;
            accB[p] += b.x * t.x + b.y * t.y + b.z * t.z + b.w * t.w;
        }
    }
    size_t ob0 = (size_t)(n * NCH + d0) * HW + p0 + pp0;
    #pragma unroll
    for (int p = 0; p < 8; ++p) dout[ob0 + p] = accA[p];
    #pragma unroll
    for (int p = 0; p < 8; ++p) dout[ob0 + HW + p] = accB[p];
}

extern "C" void kernel_launch(void* const* d_in, const int* in_sizes, int n_in,
                              void* d_out, int out_size, void* d_ws, size_t ws_size,
                              hipStream_t stream) {
    const float* ref     = (const float*)d_in[0];
    const float* input   = (const float*)d_in[1];
    const float* value_w = (const float*)d_in[2];
    const float* value_b = (const float*)d_in[3];
    const float* dw_w    = (const float*)d_in[4];
    const float* dw_b    = (const float*)d_in[5];
    const float* om_w    = (const float*)d_in[6];
    const float* om_b    = (const float*)d_in[7];
    const float* out_w   = (const float*)d_in[8];
    const float* out_b   = (const float*)d_in[9];
    float* out = (float*)d_out;

    float* xv  = (float*)d_ws;                       // [N][HW][256]  51.4 MB
    float* dwb = xv + (size_t)NB * HW * 256;         // [N][256][HW]  51.4 MB
    float* om  = dwb + (size_t)NB * HW * 256;        // [N][HW][216]  43.4 MB

    proj_kernel<256><<<NB * (HW / 32), 256, 0, stream>>>(input, value_w, value_b, xv);
    dwconv_kernel<<<NB * HEI * 64, 256, 0, stream>>>(input, ref, dw_w, dw_b, dwb);
    proj_kernel<216><<<NB * (HW / 32), 256, 0, stream>>>(dwb, om_w, om_b, om);
    sample_out_kernel<<<NB * (HW / 16), 256, 0, stream>>>(xv, om, out_w, out_b, out);
}

// Round 4
// 374.889 us; speedup vs baseline: 2.3797x; 2.2185x over previous
//
#include <hip/hip_runtime.h>

#define HW 3136
#define WID 56
#define HEI 56
#define NCH 256
#define NB 16

typedef __attribute__((ext_vector_type(8))) short bf16x8;
typedef __attribute__((ext_vector_type(8))) unsigned short u16x8;
typedef __attribute__((ext_vector_type(4))) float f32x4;

__device__ __forceinline__ unsigned int f2bf(float f) {
    unsigned int x = __float_as_uint(f);
    return (x + 0x7fffu + ((x >> 16) & 1u)) >> 16;  // RNE
}
__device__ __forceinline__ float bf2f(unsigned short u) {
    return __uint_as_float(((unsigned int)u) << 16);
}

// ---------------------------------------------------------------------------
// Weight conversion fp32 -> bf16 (value_w 65536, om_w 55296, out_w 65536)
// ---------------------------------------------------------------------------
__global__ __launch_bounds__(256) void cvt_weights(const float* __restrict__ vw,
                                                   const float* __restrict__ ow,
                                                   const float* __restrict__ outw,
                                                   unsigned short* __restrict__ dvw,
                                                   unsigned short* __restrict__ dow,
                                                   unsigned short* __restrict__ doutw) {
    int i = blockIdx.x * 256 + threadIdx.x;
    if (i < 65536) dvw[i] = (unsigned short)f2bf(vw[i]);
    else if (i < 120832) dow[i - 65536] = (unsigned short)f2bf(ow[i - 65536]);
    else if (i < 186368) doutw[i - 120832] = (unsigned short)f2bf(outw[i - 120832]);
}

// ---------------------------------------------------------------------------
// MFMA bf16 GEMM: out[m][d] = sum_k A[m][k] * W[d][k] + bias[d]
//   A_MODE 0: A fp32 NCHW [n][256][HW] (convert while staging)
//   A_MODE 1: A bf16 NCHW [n][256][HW]
//   A_MODE 2: A bf16 NHWC [n][HW][256]
//   OUT_MODE 0: fp32 [n][HW][DOUT] (stride DOUT, guard ch<DOUT)
//   OUT_MODE 1: bf16 [n][HW][256]
//   OUT_MODE 2: fp32 NCHW [n][256][HW] (float4 stores)
// Tile: BM=64 px, BN=128 ch, BK=64, 4 waves (2M x 2N), per-wave 32x64.
// LDS XOR-swizzle byte ^= (row&7)<<4 on both write and read (T2).
// ---------------------------------------------------------------------------
template <int DOUT, int A_MODE, int OUT_MODE>
__global__ __launch_bounds__(256) void gemm_kernel(const void* __restrict__ Aptr,
                                                   const unsigned short* __restrict__ Bw,
                                                   const float* __restrict__ bias,
                                                   void* __restrict__ Out) {
    int bid = blockIdx.x;
    int nt = bid & 1;
    int mt = (bid >> 1) % 49;
    int n = (bid >> 1) / 49;
    int p0 = mt * 64;
    int tid = threadIdx.x;
    int lane = tid & 63;
    int wv = tid >> 6;
    int wm = wv & 1, wn = wv >> 1;
    int n0 = nt * 128;

    __shared__ __align__(16) char lds[8192 + 16384];
    char* As = lds;
    char* Bs = lds + 8192;

    int l15 = lane & 15;
    int l4 = lane >> 4;

    // acc init with bias
    f32x4 acc[2][4];
    #pragma unroll
    for (int nf = 0; nf < 4; ++nf) {
        int ch = n0 + wn * 64 + nf * 16 + l15;
        float bv = (ch < DOUT) ? bias[ch] : 0.f;
        #pragma unroll
        for (int mf = 0; mf < 2; ++mf) acc[mf][nf] = (f32x4){bv, bv, bv, bv};
    }

    for (int t = 0; t < 4; ++t) {
        int k0 = t * 64;
        // ---- stage A ----
        if (A_MODE == 0) {
            int px = tid & 63, kq = tid >> 6;
            const float* src = (const float*)Aptr + ((size_t)(n * 256 + k0 + kq * 16)) * HW + p0 + px;
            #pragma unroll
            for (int h = 0; h < 2; ++h) {
                u16x8 v;
                #pragma unroll
                for (int j = 0; j < 8; ++j) v[j] = (unsigned short)f2bf(src[(size_t)(h * 8 + j) * HW]);
                int byte = (px * 128 + (kq * 16 + h * 8) * 2) ^ ((px & 7) << 4);
                *(u16x8*)(As + byte) = v;
            }
        } else if (A_MODE == 1) {
            int px = tid & 63, kq = tid >> 6;
            const unsigned short* src = (const unsigned short*)Aptr + ((size_t)(n * 256 + k0 + kq * 16)) * HW + p0 + px;
            #pragma unroll
            for (int h = 0; h < 2; ++h) {
                u16x8 v;
                #pragma unroll
                for (int j = 0; j < 8; ++j) v[j] = src[(size_t)(h * 8 + j) * HW];
                int byte = (px * 128 + (kq * 16 + h * 8) * 2) ^ ((px & 7) << 4);
                *(u16x8*)(As + byte) = v;
            }
        } else {
            int row = tid >> 2, q = tid & 3;
            const unsigned short* src = (const unsigned short*)Aptr + ((size_t)(n * HW) + p0 + row) * 256 + k0 + q * 16;
            #pragma unroll
            for (int h = 0; h < 2; ++h) {
                u16x8 v = *(const u16x8*)(src + h * 8);
                int byte = (row * 128 + (q * 16 + h * 8) * 2) ^ ((row & 7) << 4);
                *(u16x8*)(As + byte) = v;
            }
        }
        // ---- stage B ----
        {
            int bch = tid >> 1, kh = tid & 1;
            int ch = n0 + bch;
            bool valid = (ch < DOUT);
            const unsigned short* src = Bw + (size_t)ch * 256 + k0 + kh * 32;
            #pragma unroll
            for (int q = 0; q < 4; ++q) {
                u16x8 v = (u16x8){0, 0, 0, 0, 0, 0, 0, 0};
                if (valid) v = *(const u16x8*)(src + q * 8);
                int byte = (bch * 128 + (kh * 32 + q * 8) * 2) ^ ((bch & 7) << 4);
                *(u16x8*)(Bs + byte) = v;
            }
        }
        __syncthreads();
        // ---- compute ----
        bf16x8 af[2][2], bfr[4][2];
        #pragma unroll
        for (int mf = 0; mf < 2; ++mf)
            #pragma unroll
            for (int kf = 0; kf < 2; ++kf) {
                int row = wm * 32 + mf * 16 + l15;
                int byte = (row * 128 + (kf * 32 + l4 * 8) * 2) ^ ((row & 7) << 4);
                af[mf][kf] = *(bf16x8*)(As + byte);
            }
        #pragma unroll
        for (int nf = 0; nf < 4; ++nf)
            #pragma unroll
            for (int kf = 0; kf < 2; ++kf) {
                int row = wn * 64 + nf * 16 + l15;
                int byte = (row * 128 + (kf * 32 + l4 * 8) * 2) ^ ((row & 7) << 4);
                bfr[nf][kf] = *(bf16x8*)(Bs + byte);
            }
        #pragma unroll
        for (int mf = 0; mf < 2; ++mf)
            #pragma unroll
            for (int nf = 0; nf < 4; ++nf)
                #pragma unroll
                for (int kf = 0; kf < 2; ++kf)
                    acc[mf][nf] = __builtin_amdgcn_mfma_f32_16x16x32_bf16(af[mf][kf], bfr[nf][kf], acc[mf][nf], 0, 0, 0);
        __syncthreads();
    }

    // ---- store ----
    #pragma unroll
    for (int mf = 0; mf < 2; ++mf) {
        int pxb = p0 + wm * 32 + mf * 16 + l4 * 4;
        #pragma unroll
        for (int nf = 0; nf < 4; ++nf) {
            int ch = n0 + wn * 64 + nf * 16 + l15;
            if (OUT_MODE == 0) {
                if (ch < DOUT) {
                    float* o = (float*)Out + ((size_t)n * HW + pxb) * DOUT + ch;
                    #pragma unroll
                    for (int j = 0; j < 4; ++j) o[(size_t)j * DOUT] = acc[mf][nf][j];
                }
            } else if (OUT_MODE == 1) {
                unsigned short* o = (unsigned short*)Out + ((size_t)n * HW + pxb) * 256 + ch;
                #pragma unroll
                for (int j = 0; j < 4; ++j) o[(size_t)j * 256] = (unsigned short)f2bf(acc[mf][nf][j]);
            } else {
                float* o = (float*)Out + ((size_t)(n * 256 + ch)) * HW + pxb;
                *(f32x4*)o = acc[mf][nf];
            }
        }
    }
}

// ---------------------------------------------------------------------------
// Grouped 3x3 conv, feature_group_count=C; bf16 NCHW output.
// ---------------------------------------------------------------------------
__global__ __launch_bounds__(256) void dwconv_kernel(const float* __restrict__ input,
                                                     const float* __restrict__ ref,
                                                     const float* __restrict__ dw_w,
                                                     const float* __restrict__ dw_b,
                                                     unsigned short* __restrict__ out) {
    int blk = blockIdx.x;
    int cb = blk & 63;
    int y = (blk >> 6) % HEI;
    int n = blk / (64 * HEI);
    int tid = threadIdx.x;
    int x = tid & 63;
    int c = cb * 4 + (tid >> 6);

    const float* src = (c < 128) ? input : ref;
    int ch0 = (c < 128) ? (2 * c) : (2 * c - 256);

    float wreg[18];
    #pragma unroll
    for (int i = 0; i < 18; ++i) wreg[i] = dw_w[c * 18 + i];

    if (x < WID) {
        float acc = dw_b[c];
        #pragma unroll
        for (int i = 0; i < 2; ++i) {
            const float* base = src + (size_t)(n * NCH + ch0 + i) * HW;
            #pragma unroll
            for (int ky = 0; ky < 3; ++ky) {
                int yy = y + ky - 1;
                if (yy >= 0 && yy < HEI) {
                    const float* row = base + yy * WID;
                    #pragma unroll
                    for (int kx = 0; kx < 3; ++kx) {
                        int xx = x + kx - 1;
                        float v = (xx >= 0 && xx < WID) ? row[xx] : 0.f;
                        acc += v * wreg[i * 9 + ky * 3 + kx];
                    }
                }
            }
        }
        out[(size_t)(n * NCH + c) * HW + y * WID + x] = (unsigned short)f2bf(acc);
    }
}

// ---------------------------------------------------------------------------
// Sampler: bilinear gather from bf16 xv (NHWC), writes bf16 sout (NHWC).
// Phase 0: per (pix,g,pt) weights+indices -> LDS. Phase 1: gather-accumulate.
// ---------------------------------------------------------------------------
__global__ __launch_bounds__(256) void sample_kernel(const unsigned short* __restrict__ xv,
                                                     const float* __restrict__ om,
                                                     unsigned short* __restrict__ sout) {
    int blk = blockIdx.x;
    int n = blk / (HW / 16);
    int p0 = (blk % (HW / 16)) * 16;
    int tid = threadIdx.x;

    __shared__ __align__(16) float swt[1152][4];
    __shared__ __align__(8) ushort soff[1152][4];

    for (int i = tid; i < 1152; i += 256) {
        int pix = i / 72;
        int r = i % 72;
        int g = r / 9;
        int pt = r % 9;
        int glob = p0 + pix;
        int py = glob / WID, px = glob % WID;
        const float* ob = om + ((size_t)n * HW + glob) * 216 + g * 27;
        float ox = ob[2 * pt];
        float oy = ob[2 * pt + 1];
        float m = ob[18 + pt];
        float iy = (float)(py + pt / 3 - 1) + oy;
        float ix = (float)(px + pt % 3 - 1) + ox;
        float fy0 = floorf(iy), fx0 = floorf(ix);
        float fy = iy - fy0, fx = ix - fx0;
        int y0 = (int)fy0, x0 = (int)fx0;
        #pragma unroll
        for (int dy = 0; dy < 2; ++dy) {
            #pragma unroll
            for (int dx = 0; dx < 2; ++dx) {
                int yy = y0 + dy, xx = x0 + dx;
                bool valid = (yy >= 0) & (yy < HEI) & (xx >= 0) & (xx < WID);
                int yc = min(max(yy, 0), HEI - 1);
                int xc = min(max(xx, 0), WID - 1);
                float wv = (dy ? fy : 1.f - fy) * (dx ? fx : 1.f - fx) * m;
                swt[i][dy * 2 + dx] = valid ? wv : 0.f;
                soff[i][dy * 2 + dx] = (ushort)(yc * WID + xc);
            }
        }
    }
    __syncthreads();

    int pix = tid >> 4;
    int gp = (tid >> 3) & 1;
    int c4 = tid & 7;
    float4 acc[4];
    #pragma unroll
    for (int i = 0; i < 4; ++i) acc[i] = make_float4(0.f, 0.f, 0.f, 0.f);

    const unsigned short* xvb = xv + (size_t)n * HW * 256;
    #pragma unroll
    for (int i = 0; i < 4; ++i) {
        int g = gp + 2 * i;
        int widx = pix * 72 + g * 9;
        const unsigned short* xc = xvb + g * 32 + c4 * 4;
        #pragma unroll
        for (int pt = 0; pt < 9; ++pt) {
            float4 w = *(const float4*)&swt[widx + pt][0];
            ushort4 o = *(const ushort4*)&soff[widx + pt][0];
            ushort4 r0 = *(const ushort4*)(xc + (size_t)o.x * 256);
            ushort4 r1 = *(const ushort4*)(xc + (size_t)o.y * 256);
            ushort4 r2 = *(const ushort4*)(xc + (size_t)o.z * 256);
            ushort4 r3 = *(const ushort4*)(xc + (size_t)o.w * 256);
            acc[i].x += w.x * bf2f(r0.x) + w.y * bf2f(r1.x) + w.z * bf2f(r2.x) + w.w * bf2f(r3.x);
            acc[i].y += w.x * bf2f(r0.y) + w.y * bf2f(r1.y) + w.z * bf2f(r2.y) + w.w * bf2f(r3.y);
            acc[i].z += w.x * bf2f(r0.z) + w.y * bf2f(r1.z) + w.z * bf2f(r2.z) + w.w * bf2f(r3.z);
            acc[i].w += w.x * bf2f(r0.w) + w.y * bf2f(r1.w) + w.z * bf2f(r2.w) + w.w * bf2f(r3.w);
        }
    }
    unsigned short* so = sout + ((size_t)n * HW + p0 + pix) * 256;
    #pragma unroll
    for (int i = 0; i < 4; ++i) {
        int g = gp + 2 * i;
        ushort4 st = make_ushort4((unsigned short)f2bf(acc[i].x), (unsigned short)f2bf(acc[i].y),
                                  (unsigned short)f2bf(acc[i].z), (unsigned short)f2bf(acc[i].w));
        *(ushort4*)(so + g * 32 + c4 * 4) = st;
    }
}

extern "C" void kernel_launch(void* const* d_in, const int* in_sizes, int n_in,
                              void* d_out, int out_size, void* d_ws, size_t ws_size,
                              hipStream_t stream) {
    const float* ref     = (const float*)d_in[0];
    const float* input   = (const float*)d_in[1];
    const float* value_w = (const float*)d_in[2];
    const float* value_b = (const float*)d_in[3];
    const float* dw_w    = (const float*)d_in[4];
    const float* dw_b    = (const float*)d_in[5];
    const float* om_w    = (const float*)d_in[6];
    const float* om_b    = (const float*)d_in[7];
    const float* out_w   = (const float*)d_in[8];
    const float* out_b   = (const float*)d_in[9];
    float* out = (float*)d_out;

    char* ws = (char*)d_ws;
    const size_t BF = (size_t)NB * HW * 256 * 2;          // 25.7 MB per bf16 tensor
    unsigned short* xv   = (unsigned short*)(ws);
    unsigned short* dwb  = (unsigned short*)(ws + BF);
    unsigned short* sout = (unsigned short*)(ws + 2 * BF);
    float* om            = (float*)(ws + 3 * BF);         // 43.3 MB
    char* wbase          = ws + 3 * BF + (size_t)NB * HW * 216 * 4;
    unsigned short* vw_bf   = (unsigned short*)(wbase);
    unsigned short* ow_bf   = (unsigned short*)(wbase + 131072);
    unsigned short* outw_bf = (unsigned short*)(wbase + 131072 + 110592);

    cvt_weights<<<728, 256, 0, stream>>>(value_w, om_w, out_w, vw_bf, ow_bf, outw_bf);
    gemm_kernel<256, 0, 1><<<NB * 49 * 2, 256, 0, stream>>>(input, vw_bf, value_b, xv);
    dwconv_kernel<<<NB * HEI * 64, 256, 0, stream>>>(input, ref, dw_w, dw_b, dwb);
    gemm_kernel<216, 1, 0><<<NB * 49 * 2, 256, 0, stream>>>(dwb, ow_bf, om_b, om);
    sample_kernel<<<NB * (HW / 16), 256, 0, stream>>>(xv, om, sout);
    gemm_kernel<256, 2, 2><<<NB * 49 * 2, 256, 0, stream>>>(sout, outw_bf, out_b, out);
}

// Round 5
// 291.768 us; speedup vs baseline: 3.0576x; 1.2849x over previous
//
#include <hip/hip_runtime.h>

#define HW 3136
#define WID 56
#define HEI 56
#define NCH 256
#define NB 16

typedef __attribute__((ext_vector_type(8))) short bf16x8;
typedef __attribute__((ext_vector_type(8))) unsigned short u16x8;
typedef __attribute__((ext_vector_type(4))) float f32x4;

__device__ __forceinline__ unsigned int f2bf(float f) {
    unsigned int x = __float_as_uint(f);
    return (x + 0x7fffu + ((x >> 16) & 1u)) >> 16;  // RNE
}
__device__ __forceinline__ float bf2f(unsigned short u) {
    return __uint_as_float(((unsigned int)u) << 16);
}

// ---------------------------------------------------------------------------
// Weight conversion fp32 -> bf16 (value_w 65536, om_w 55296, out_w 65536)
// ---------------------------------------------------------------------------
__global__ __launch_bounds__(256) void cvt_weights(const float* __restrict__ vw,
                                                   const float* __restrict__ ow,
                                                   const float* __restrict__ outw,
                                                   unsigned short* __restrict__ dvw,
                                                   unsigned short* __restrict__ dow,
                                                   unsigned short* __restrict__ doutw) {
    int i = blockIdx.x * 256 + threadIdx.x;
    if (i < 65536) dvw[i] = (unsigned short)f2bf(vw[i]);
    else if (i < 120832) dow[i - 65536] = (unsigned short)f2bf(ow[i - 65536]);
    else if (i < 186368) doutw[i - 120832] = (unsigned short)f2bf(outw[i - 120832]);
}

// ---------------------------------------------------------------------------
// MFMA bf16 GEMM: out[m][d] = sum_k A[m][k] * W[d][k] + bias[d]
//   A_MODE 0: A fp32 NCHW; A_MODE 1: A bf16 NCHW; A_MODE 2: A bf16 NHWC
//   OUT_MODE 0: fp32 [n][HW][DOUT]; OUT_MODE 1: bf16 NHWC; OUT_MODE 2: fp32 NCHW
// Tile: BM=64 px, BN=128 ch, BK=64, 4 waves (2M x 2N), per-wave 32x64.
// LDS XOR-swizzle byte ^= (row&7)<<4 on write and read (T2).
// ---------------------------------------------------------------------------
template <int DOUT, int A_MODE, int OUT_MODE>
__global__ __launch_bounds__(256) void gemm_kernel(const void* __restrict__ Aptr,
                                                   const unsigned short* __restrict__ Bw,
                                                   const float* __restrict__ bias,
                                                   void* __restrict__ Out) {
    int bid = blockIdx.x;
    int nt = bid & 1;
    int mt = (bid >> 1) % 49;
    int n = (bid >> 1) / 49;
    int p0 = mt * 64;
    int tid = threadIdx.x;
    int lane = tid & 63;
    int wv = tid >> 6;
    int wm = wv & 1, wn = wv >> 1;
    int n0 = nt * 128;

    __shared__ __align__(16) char lds[8192 + 16384];
    char* As = lds;
    char* Bs = lds + 8192;

    int l15 = lane & 15;
    int l4 = lane >> 4;

    f32x4 acc[2][4];
    #pragma unroll
    for (int nf = 0; nf < 4; ++nf) {
        int ch = n0 + wn * 64 + nf * 16 + l15;
        float bv = (ch < DOUT) ? bias[ch] : 0.f;
        #pragma unroll
        for (int mf = 0; mf < 2; ++mf) acc[mf][nf] = (f32x4){bv, bv, bv, bv};
    }

    for (int t = 0; t < 4; ++t) {
        int k0 = t * 64;
        // ---- stage A ----
        if (A_MODE == 0) {
            int px = tid & 63, kq = tid >> 6;
            const float* src = (const float*)Aptr + ((size_t)(n * 256 + k0 + kq * 16)) * HW + p0 + px;
            #pragma unroll
            for (int h = 0; h < 2; ++h) {
                u16x8 v;
                #pragma unroll
                for (int j = 0; j < 8; ++j) v[j] = (unsigned short)f2bf(src[(size_t)(h * 8 + j) * HW]);
                int byte = (px * 128 + (kq * 16 + h * 8) * 2) ^ ((px & 7) << 4);
                *(u16x8*)(As + byte) = v;
            }
        } else if (A_MODE == 1) {
            int px = tid & 63, kq = tid >> 6;
            const unsigned short* src = (const unsigned short*)Aptr + ((size_t)(n * 256 + k0 + kq * 16)) * HW + p0 + px;
            #pragma unroll
            for (int h = 0; h < 2; ++h) {
                u16x8 v;
                #pragma unroll
                for (int j = 0; j < 8; ++j) v[j] = src[(size_t)(h * 8 + j) * HW];
                int byte = (px * 128 + (kq * 16 + h * 8) * 2) ^ ((px & 7) << 4);
                *(u16x8*)(As + byte) = v;
            }
        } else {
            int row = tid >> 2, q = tid & 3;
            const unsigned short* src = (const unsigned short*)Aptr + ((size_t)(n * HW) + p0 + row) * 256 + k0 + q * 16;
            #pragma unroll
            for (int h = 0; h < 2; ++h) {
                u16x8 v = *(const u16x8*)(src + h * 8);
                int byte = (row * 128 + (q * 16 + h * 8) * 2) ^ ((row & 7) << 4);
                *(u16x8*)(As + byte) = v;
            }
        }
        // ---- stage B ----
        {
            int bch = tid >> 1, kh = tid & 1;
            int ch = n0 + bch;
            bool valid = (ch < DOUT);
            const unsigned short* src = Bw + (size_t)ch * 256 + k0 + kh * 32;
            #pragma unroll
            for (int q = 0; q < 4; ++q) {
                u16x8 v = (u16x8){0, 0, 0, 0, 0, 0, 0, 0};
                if (valid) v = *(const u16x8*)(src + q * 8);
                int byte = (bch * 128 + (kh * 32 + q * 8) * 2) ^ ((bch & 7) << 4);
                *(u16x8*)(Bs + byte) = v;
            }
        }
        __syncthreads();
        // ---- compute ----
        bf16x8 af[2][2], bfr[4][2];
        #pragma unroll
        for (int mf = 0; mf < 2; ++mf)
            #pragma unroll
            for (int kf = 0; kf < 2; ++kf) {
                int row = wm * 32 + mf * 16 + l15;
                int byte = (row * 128 + (kf * 32 + l4 * 8) * 2) ^ ((row & 7) << 4);
                af[mf][kf] = *(bf16x8*)(As + byte);
            }
        #pragma unroll
        for (int nf = 0; nf < 4; ++nf)
            #pragma unroll
            for (int kf = 0; kf < 2; ++kf) {
                int row = wn * 64 + nf * 16 + l15;
                int byte = (row * 128 + (kf * 32 + l4 * 8) * 2) ^ ((row & 7) << 4);
                bfr[nf][kf] = *(bf16x8*)(Bs + byte);
            }
        #pragma unroll
        for (int mf = 0; mf < 2; ++mf)
            #pragma unroll
            for (int nf = 0; nf < 4; ++nf)
                #pragma unroll
                for (int kf = 0; kf < 2; ++kf)
                    acc[mf][nf] = __builtin_amdgcn_mfma_f32_16x16x32_bf16(af[mf][kf], bfr[nf][kf], acc[mf][nf], 0, 0, 0);
        __syncthreads();
    }

    // ---- store ----
    #pragma unroll
    for (int mf = 0; mf < 2; ++mf) {
        int pxb = p0 + wm * 32 + mf * 16 + l4 * 4;
        #pragma unroll
        for (int nf = 0; nf < 4; ++nf) {
            int ch = n0 + wn * 64 + nf * 16 + l15;
            if (OUT_MODE == 0) {
                if (ch < DOUT) {
                    float* o = (float*)Out + ((size_t)n * HW + pxb) * DOUT + ch;
                    #pragma unroll
                    for (int j = 0; j < 4; ++j) o[(size_t)j * DOUT] = acc[mf][nf][j];
                }
            } else if (OUT_MODE == 1) {
                unsigned short* o = (unsigned short*)Out + ((size_t)n * HW + pxb) * 256 + ch;
                #pragma unroll
                for (int j = 0; j < 4; ++j) o[(size_t)j * 256] = (unsigned short)f2bf(acc[mf][nf][j]);
            } else {
                float* o = (float*)Out + ((size_t)(n * 256 + ch)) * HW + pxb;
                *(f32x4*)o = acc[mf][nf];
            }
        }
    }
}

// ---------------------------------------------------------------------------
// Grouped 3x3 conv, register-blocked: each thread computes 4 y-outputs for
// one channel. Tap rows y0-1..y0+4 loaded once, reused across the 3
// overlapping windows (72 FMA per 36 loads). bf16 NCHW output.
// Grid: n(16) x cb(64) x yt(14); thread: x = tid&63, c = cb*4 + (tid>>6).
// ---------------------------------------------------------------------------
__global__ __launch_bounds__(256) void dwconv_kernel(const float* __restrict__ input,
                                                     const float* __restrict__ ref,
                                                     const float* __restrict__ dw_w,
                                                     const float* __restrict__ dw_b,
                                                     unsigned short* __restrict__ out) {
    int blk = blockIdx.x;
    int yt = blk % 14;
    int cb = (blk / 14) & 63;
    int n = blk / (14 * 64);
    int tid = threadIdx.x;
    int x = tid & 63;
    int c = cb * 4 + (tid >> 6);
    int y0 = yt * 4;

    const float* src = (c < 128) ? input : ref;
    int ch0 = (c < 128) ? (2 * c) : (2 * c - 256);

    float w[18];
    #pragma unroll
    for (int i = 0; i < 18; ++i) w[i] = dw_w[c * 18 + i];

    if (x < WID) {
        float bv = dw_b[c];
        float acc[4] = {bv, bv, bv, bv};
        #pragma unroll
        for (int ch = 0; ch < 2; ++ch) {
            const float* base = src + (size_t)(n * NCH + ch0 + ch) * HW;
            #pragma unroll
            for (int r = 0; r < 6; ++r) {
                int yy = y0 - 1 + r;
                bool vy = (yy >= 0) && (yy < HEI);
                const float* row = base + yy * WID;
                float lt = (vy && x > 0) ? row[x - 1] : 0.f;
                float md = vy ? row[x] : 0.f;
                float rt = (vy && x < WID - 1) ? row[x + 1] : 0.f;
                #pragma unroll
                for (int o = 0; o < 4; ++o) {
                    int ky = r - o;  // output y0+o uses rows r = o..o+2
                    if (ky >= 0 && ky < 3) {
                        acc[o] += lt * w[ch * 9 + ky * 3 + 0] + md * w[ch * 9 + ky * 3 + 1] + rt * w[ch * 9 + ky * 3 + 2];
                    }
                }
            }
        }
        unsigned short* o = out + (size_t)(n * NCH + c) * HW + y0 * WID + x;
        #pragma unroll
        for (int j = 0; j < 4; ++j) o[j * WID] = (unsigned short)f2bf(acc[j]);
    }
}

// ---------------------------------------------------------------------------
// Sampler: bilinear gather from bf16 xv (NHWC), writes bf16 sout (NHWC).
// Phase 0: per (pix,g,pt) weights+indices -> LDS.
// Phase 1: thread = (pix = tid>>4, t16 = tid&15); 2 chunks of 8 channels
//          ({t16, t16+16}, chunk = g*4+c8); per corner one 16B gather.
// ---------------------------------------------------------------------------
__global__ __launch_bounds__(256) void sample_kernel(const unsigned short* __restrict__ xv,
                                                     const float* __restrict__ om,
                                                     unsigned short* __restrict__ sout) {
    int blk = blockIdx.x;
    int n = blk / (HW / 16);
    int p0 = (blk % (HW / 16)) * 16;
    int tid = threadIdx.x;

    __shared__ __align__(16) float swt[1152][4];
    __shared__ __align__(8) ushort soff[1152][4];

    for (int i = tid; i < 1152; i += 256) {
        int pix = i / 72;
        int r = i % 72;
        int g = r / 9;
        int pt = r % 9;
        int glob = p0 + pix;
        int py = glob / WID, px = glob % WID;
        const float* ob = om + ((size_t)n * HW + glob) * 216 + g * 27;
        float ox = ob[2 * pt];
        float oy = ob[2 * pt + 1];
        float m = ob[18 + pt];
        float iy = (float)(py + pt / 3 - 1) + oy;
        float ix = (float)(px + pt % 3 - 1) + ox;
        float fy0 = floorf(iy), fx0 = floorf(ix);
        float fy = iy - fy0, fx = ix - fx0;
        int y0 = (int)fy0, x0 = (int)fx0;
        #pragma unroll
        for (int dy = 0; dy < 2; ++dy) {
            #pragma unroll
            for (int dx = 0; dx < 2; ++dx) {
                int yy = y0 + dy, xx = x0 + dx;
                bool valid = (yy >= 0) & (yy < HEI) & (xx >= 0) & (xx < WID);
                int yc = min(max(yy, 0), HEI - 1);
                int xc = min(max(xx, 0), WID - 1);
                float wv = (dy ? fy : 1.f - fy) * (dx ? fx : 1.f - fx) * m;
                swt[i][dy * 2 + dx] = valid ? wv : 0.f;
                soff[i][dy * 2 + dx] = (ushort)(yc * WID + xc);
            }
        }
    }
    __syncthreads();

    int pix = tid >> 4;
    int t16 = tid & 15;
    const unsigned short* xvb = xv + (size_t)n * HW * 256;
    unsigned short* so = sout + ((size_t)n * HW + p0 + pix) * 256;

    #pragma unroll
    for (int i = 0; i < 2; ++i) {
        int chunk = t16 + 16 * i;
        int g = chunk >> 2, c8 = chunk & 3;
        int widx = pix * 72 + g * 9;
        const unsigned short* xc = xvb + g * 32 + c8 * 8;
        float acc[8];
        #pragma unroll
        for (int j = 0; j < 8; ++j) acc[j] = 0.f;
        #pragma unroll
        for (int pt = 0; pt < 9; ++pt) {
            float4 w = *(const float4*)&swt[widx + pt][0];
            ushort4 o = *(const ushort4*)&soff[widx + pt][0];
            u16x8 r0 = *(const u16x8*)(xc + (size_t)o.x * 256);
            u16x8 r1 = *(const u16x8*)(xc + (size_t)o.y * 256);
            u16x8 r2 = *(const u16x8*)(xc + (size_t)o.z * 256);
            u16x8 r3 = *(const u16x8*)(xc + (size_t)o.w * 256);
            #pragma unroll
            for (int j = 0; j < 8; ++j) {
                acc[j] += w.x * bf2f(r0[j]) + w.y * bf2f(r1[j]) + w.z * bf2f(r2[j]) + w.w * bf2f(r3[j]);
            }
        }
        u16x8 st;
        #pragma unroll
        for (int j = 0; j < 8; ++j) st[j] = (unsigned short)f2bf(acc[j]);
        *(u16x8*)(so + g * 32 + c8 * 8) = st;
    }
}

extern "C" void kernel_launch(void* const* d_in, const int* in_sizes, int n_in,
                              void* d_out, int out_size, void* d_ws, size_t ws_size,
                              hipStream_t stream) {
    const float* ref     = (const float*)d_in[0];
    const float* input   = (const float*)d_in[1];
    const float* value_w = (const float*)d_in[2];
    const float* value_b = (const float*)d_in[3];
    const float* dw_w    = (const float*)d_in[4];
    const float* dw_b    = (const float*)d_in[5];
    const float* om_w    = (const float*)d_in[6];
    const float* om_b    = (const float*)d_in[7];
    const float* out_w   = (const float*)d_in[8];
    const float* out_b   = (const float*)d_in[9];
    float* out = (float*)d_out;

    char* ws = (char*)d_ws;
    const size_t BF = (size_t)NB * HW * 256 * 2;          // 25.7 MB per bf16 tensor
    unsigned short* xv   = (unsigned short*)(ws);
    unsigned short* dwb  = (unsigned short*)(ws + BF);
    unsigned short* sout = (unsigned short*)(ws + 2 * BF);
    float* om            = (float*)(ws + 3 * BF);         // 43.3 MB
    char* wbase          = ws + 3 * BF + (size_t)NB * HW * 216 * 4;
    unsigned short* vw_bf   = (unsigned short*)(wbase);
    unsigned short* ow_bf   = (unsigned short*)(wbase + 131072);
    unsigned short* outw_bf = (unsigned short*)(wbase + 131072 + 110592);

    cvt_weights<<<728, 256, 0, stream>>>(value_w, om_w, out_w, vw_bf, ow_bf, outw_bf);
    gemm_kernel<256, 0, 1><<<NB * 49 * 2, 256, 0, stream>>>(input, vw_bf, value_b, xv);
    dwconv_kernel<<<NB * 64 * 14, 256, 0, stream>>>(input, ref, dw_w, dw_b, dwb);
    gemm_kernel<216, 1, 0><<<NB * 49 * 2, 256, 0, stream>>>(dwb, ow_bf, om_b, om);
    sample_kernel<<<NB * (HW / 16), 256, 0, stream>>>(xv, om, sout);
    gemm_kernel<256, 2, 2><<<NB * 49 * 2, 256, 0, stream>>>(sout, outw_bf, out_b, out);
}